// Round 6
// baseline (524.440 us; speedup 1.0000x reference)
//
#include <hip/hip_runtime.h>
#include <stdint.h>

#define NTOK 65536
#define DIM  768
#define NCB  512
#define NC   510
#define TAU  0.75f

typedef _Float16 f16x8 __attribute__((ext_vector_type(8)));
typedef float f32x4 __attribute__((ext_vector_type(4)));

// ws byte offsets
#define WS_C32   0u          // 512*768*4
#define WS_CHI   1572864u    // 512*768*2   (f16)
#define WS_CNORM 3145728u    // 512*4
#define WS_G     3147776u    // 512*512*4
#define WS_IDX   4196352u    // 65536*8*4 (fallback path only)
#define WS_PART  6293504u    // 16384*4 loss partials
#define WS_S     8388608u    // S f16: 65536*512*2
#define S_BYTES  67108864u

__device__ __forceinline__ void gl_lds16(const void* g, void* l){
  __builtin_amdgcn_global_load_lds(
      (const __attribute__((address_space(1))) unsigned int*)g,
      (__attribute__((address_space(3))) unsigned int*)l,
      16, 0, 0);
}

__global__ void k_prep(const float* __restrict__ cb0, const float* __restrict__ cb1,
                       const float* __restrict__ cb2, const float* __restrict__ cb3,
                       const float* __restrict__ cb4, const float* __restrict__ cb5,
                       const float* __restrict__ cb6, const float* __restrict__ cb7,
                       char* __restrict__ ws){
  const int r = blockIdx.x, t = threadIdx.x;
  const float* srcs[8] = {cb0,cb1,cb2,cb3,cb4,cb5,cb6,cb7};
  const int off[8] = {0,2,6,14,30,62,126,254};
  const int KK[8]  = {2,4,8,16,32,64,128,256};
  const float* src = nullptr;
#pragma unroll
  for (int l=0;l<8;l++)
    if (r >= off[l] && r < off[l]+KK[l]) src = srcs[l] + (size_t)(r - off[l]) * DIM;
  float* C32 = (float*)(ws + WS_C32);
  _Float16* Chi = (_Float16*)(ws + WS_CHI);
  double ss = 0.0;
#pragma unroll
  for (int i=0;i<3;i++){
    const int e = t + i*256;
    const float v = src ? src[e] : 0.f;
    C32[(size_t)r*DIM + e] = v;
    Chi[(size_t)r*DIM + e] = (_Float16)v;
    ss += (double)v * (double)v;
  }
  __shared__ double red[256];
  red[t] = ss; __syncthreads();
  for (int sdown=128; sdown>0; sdown>>=1){
    if (t < sdown) red[t] += red[t+sdown];
    __syncthreads();
  }
  if (t == 0){
    float* cnp = (float*)(ws + WS_CNORM);
    cnp[r] = (r < NC) ? (float)red[0] : 1e30f;
  }
}

__global__ void k_gram(char* __restrict__ ws){
  const int i = blockIdx.x, t = threadIdx.x;
  const float* __restrict__ C32 = (const float*)(ws + WS_C32);
  __shared__ float row[DIM];
  for (int e=t; e<DIM; e+=256) row[e] = C32[(size_t)i*DIM + e];
  __syncthreads();
  float* __restrict__ G = (float*)(ws + WS_G);
  for (int j=t; j<NCB; j+=256){
    const float4* cj = (const float4*)(C32 + (size_t)j*DIM);
    double d = 0.0;
    for (int k=0; k<DIM/4; k++){
      const float4 b = cj[k];
      d += (double)row[4*k]*(double)b.x + (double)row[4*k+1]*(double)b.y
         + (double)row[4*k+2]*(double)b.z + (double)row[4*k+3]*(double)b.w;
    }
    G[(size_t)i*NCB + j] = (float)d;
  }
}

// S = x @ C_all^T, single f16 pass, f32 accum, stored f16.
// 128x128 tile, BK=64, 4 waves (2Mx2N).
// LDS 48KB: A 16KB single-buffer + B 2x16KB double-buffer -> 3 blocks/CU.
// Pipeline per K-step: issue loadA(kt+1)->regs and stageB(kt+1)->B^1 BEFORE
// compute(kt), so both have a full compute phase to land (T14).
__global__ __launch_bounds__(256, 3) void k_gemm(const float* __restrict__ x,
                                                 const char* __restrict__ ws,
                                                 _Float16* __restrict__ S){
  __shared__ __align__(16) char smem[49152];
  const int t = threadIdx.x, lane = t & 63, w = t >> 6;
  const int wm = w >> 1, wn = w & 1;
  const int bid = blockIdx.x;
  const int xcd = bid & 7, jj = bid >> 3;
  const int mt = xcd*64 + (jj >> 2), nt = jj & 3;
  const _Float16* __restrict__ Chi = (const _Float16*)(ws + WS_CHI);

  f32x4 acc[4][4];
#pragma unroll
  for (int i=0;i<4;i++)
#pragma unroll
    for (int j=0;j<4;j++) acc[i][j] = {0.f,0.f,0.f,0.f};

  const int ar = t & 127, hh = t >> 7;
  const float* __restrict__ xrow = x + (size_t)(mt*128 + ar)*DIM + hh*32;

  float4 va[8];   // A prefetch registers (32 VGPR)
  auto loadA = [&](int kt){
    const float4* p = (const float4*)(xrow + (size_t)kt*64);
#pragma unroll
    for (int q=0;q<8;q++) va[q] = p[q];
  };
  auto writeA = [&](){
#pragma unroll
    for (int q=0;q<4;q++){
      const float4 v0 = va[2*q], v1 = va[2*q+1];
      f16x8 hv;
      hv[0]=(_Float16)v0.x; hv[1]=(_Float16)v0.y; hv[2]=(_Float16)v0.z; hv[3]=(_Float16)v0.w;
      hv[4]=(_Float16)v1.x; hv[5]=(_Float16)v1.y; hv[6]=(_Float16)v1.z; hv[7]=(_Float16)v1.w;
      const uint wb = (uint)(ar*128 + (((hh*4+q) ^ (ar&7))*16));
      *(f16x8*)(smem + wb) = hv;
    }
  };
  auto stageB = [&](int kt, uint base){
#pragma unroll
    for (int c4=0;c4<4;c4++){
      const int r0 = w*32 + c4*8;
      const int rloc = r0 + (lane>>3);
      const int jsrc = (lane&7) ^ (rloc&7);
      const size_t go = (size_t)(nt*128 + rloc)*DIM + (size_t)kt*64 + jsrc*8;
      gl_lds16(Chi + go, smem + base + r0*128);
    }
  };
  auto compute = [&](int kk, uint bbase){
    f16x8 fa[4], fb[4];
#pragma unroll
    for (int mf=0;mf<4;mf++){
      const int m = wm*64 + mf*16 + (lane&15);
      const uint ab = (uint)(m*128 + ((((kk<<2)+(lane>>4)) ^ (m&7))*16));
      fa[mf] = *(const f16x8*)(smem + ab);
    }
#pragma unroll
    for (int nf=0;nf<4;nf++){
      const int c = wn*64 + nf*16 + (lane&15);
      const uint bb = bbase + (uint)(c*128 + ((((kk<<2)+(lane>>4)) ^ (c&7))*16));
      fb[nf] = *(const f16x8*)(smem + bb);
    }
#pragma unroll
    for (int mf=0;mf<4;mf++)
#pragma unroll
      for (int nf=0;nf<4;nf++)
        acc[mf][nf] = __builtin_amdgcn_mfma_f32_16x16x32_f16(fa[mf], fb[nf], acc[mf][nf], 0,0,0);
  };

  // prologue
  loadA(0);
  stageB(0, 16384);
  writeA();                       // compiler waits vmcnt for va
  __syncthreads();                // A(0), B(0) ready

  for (int kt=0; kt<12; kt++){
    const uint bb = 16384u + (uint)((kt&1)*16384);
    const uint bn = 16384u + (uint)(((kt+1)&1)*16384);
    if (kt < 11){
      loadA(kt+1);                // HBM->reg, lands during compute
      stageB(kt+1, bn);           // L2->LDS (other buffer), lands during compute
    }
    compute(0, bb);
    compute(1, bb);
    __syncthreads();              // compute reads done; stageB(kt+1) drained
    if (kt < 11) writeA();        // A(kt+1) into A-lds (free now)
    __syncthreads();              // A(kt+1) visible to all waves
  }

#pragma unroll
  for (int mf=0;mf<4;mf++)
#pragma unroll
    for (int nf=0;nf<4;nf++){
      const f32x4 v = acc[mf][nf];
      const int col  = nt*128 + wn*64 + nf*16 + (lane&15);
      const int row0 = mt*128 + wm*64 + mf*16 + ((lane>>4)<<2);
#pragma unroll
      for (int e=0;e<4;e++)
        S[(size_t)(row0+e)*NCB + col] = (_Float16)v[e];
    }
}

// Band-rescore argmin chain, 1 wave/token, minimal loop live-state.
// Loop holds only sv[8]/s0[8]; selections parked in LDS; x loaded only on the
// rare rescore path and in the epilogue; residual/ssq/out all in the epilogue.
// Gram correction for rescore = s0 - sv of the owner lane (f16-S error cancels).
template<int FUSED>
__global__ __launch_bounds__(256, 4) void k_chain(const float* __restrict__ x,
                                                  const _Float16* __restrict__ S,
                                                  char* __restrict__ ws,
                                                  float* __restrict__ out,
                                                  float* __restrict__ part){
  __shared__ int mcs[4][8];
  __shared__ float bs[4];
  const int t = threadIdx.x, lane = t & 63, w = t >> 6;
  const size_t tok = (size_t)blockIdx.x*4 + w;
  const float* __restrict__ cn  = (const float*)(ws + WS_CNORM);
  const float* __restrict__ G   = (const float*)(ws + WS_G);
  const float* __restrict__ C32 = (const float*)(ws + WS_C32);

  float sv[8], s0[8];
  {
    const uint* sp = (const uint*)(S + tok*NCB);
#pragma unroll
    for (int j=0;j<4;j++){
      union { uint u; _Float16 h[2]; } cv;
      cv.u = sp[j*64 + lane];
      sv[2*j]   = (float)cv.h[0];
      sv[2*j+1] = (float)cv.h[1];
    }
  }
#pragma unroll
  for (int k=0;k<8;k++) s0[k] = sv[k];

  for (int l=0; l<8; ++l){
    const int cs = (2<<l) - 2;
    const int ce = cs + (2<<l);
    float sc[8];
    float bv = 3e38f; int bc = 0x7fffffff;
#pragma unroll
    for (int j=0;j<4;j++){
      const float2 c2 = *(const float2*)(cn + j*128 + lane*2);
      const int c0 = j*128 + lane*2;
      const float sA = (c0   >= cs && c0   < ce) ? (c2.x - 2.f*sv[2*j])   : 3e38f;
      const float sB = (c0+1 >= cs && c0+1 < ce) ? (c2.y - 2.f*sv[2*j+1]) : 3e38f;
      sc[2*j] = sA; sc[2*j+1] = sB;
      if (sA < bv){ bv = sA; bc = c0; }
      if (sB < bv){ bv = sB; bc = c0+1; }
    }
#pragma unroll
    for (int d=1; d<64; d<<=1){
      const float ov = __shfl_xor(bv, d);
      const int   oc = __shfl_xor(bc, d);
      if (ov < bv || (ov == bv && oc < bc)){ bv = ov; bc = oc; }
    }
    unsigned long long mb[8];
    int nband = 0;
#pragma unroll
    for (int k=0;k<8;k++){
      mb[k] = __ballot(sc[k] <= bv + TAU);
      nband += __popcll(mb[k]);
    }
    int mc = bc;
    if (nband > 1){
      // rare exact-rescore path: load x row here (keeps it out of loop state)
      float xv[12];
      {
        const float4* xp = (const float4*)(x + tok*DIM + lane*12);
#pragma unroll
        for (int q=0;q<3;q++){
          const float4 v = xp[q];
          xv[q*4]=v.x; xv[q*4+1]=v.y; xv[q*4+2]=v.z; xv[q*4+3]=v.w;
        }
      }
      double bve = 1e300; int bce = 0x7fffffff;
#pragma unroll
      for (int k=0;k<8;k++){
        unsigned long long m = mb[k];
        const float dk = s0[k] - sv[k];   // exact f32 gram-correction sum
        while (m){
          const int b = __ffsll((long long)m) - 1; m &= m - 1;
          const int c = (k>>1)*128 + b*2 + (k&1);
          const float* __restrict__ crow = C32 + (size_t)c*DIM + lane*12;
          double dd = 0.0;
#pragma unroll
          for (int q=0;q<3;q++){
            const float4 v = *(const float4*)(crow + q*4);
            dd += (double)xv[q*4]*v.x + (double)xv[q*4+1]*v.y
                + (double)xv[q*4+2]*v.z + (double)xv[q*4+3]*v.w;
          }
#pragma unroll
          for (int d=1; d<64; d<<=1) dd += __shfl_xor(dd, d);
          const float gcf = __shfl(dk, b);
          const double se = (double)cn[c] - 2.0*(dd - (double)gcf);
          if (se < bve || (se == bve && c < bce)){ bve = se; bce = c; }
        }
      }
      mc = bce;
    }

    if (lane == 0){
      mcs[w][l] = mc;
      if (FUSED) out[(size_t)NTOK*DIM + tok*8 + l] = (float)(mc - cs);
      else       ((int*)(ws + WS_IDX))[tok*8 + l]  = mc - cs;
    }
    if (l < 7){
      const float* __restrict__ gr = G + (size_t)mc*NCB;
#pragma unroll
      for (int j=0;j<4;j++){
        const float2 g2 = *(const float2*)(gr + j*128 + lane*2);
        sv[2*j] -= g2.x; sv[2*j+1] -= g2.y;
      }
    }
  }

  if (FUSED){
    // epilogue: residual chain + quantized + loss partial
    float xq[12], rv[12];
    {
      const float4* xp = (const float4*)(x + tok*DIM + lane*12);
#pragma unroll
      for (int q=0;q<3;q++){
        const float4 v = xp[q];
        xq[q*4]=v.x; xq[q*4+1]=v.y; xq[q*4+2]=v.z; xq[q*4+3]=v.w;
      }
    }
#pragma unroll
    for (int i=0;i<12;i++) rv[i] = xq[i];
    float ssq = 0.f;
#pragma unroll
    for (int l=0;l<8;l++){
      const int mc = mcs[w][l];     // LDS, wave-local order guarantees visibility
      const float* __restrict__ cw = C32 + (size_t)mc*DIM + lane*12;
#pragma unroll
      for (int q=0;q<3;q++){
        const float4 v = *(const float4*)(cw + q*4);
        rv[q*4]-=v.x; rv[q*4+1]-=v.y; rv[q*4+2]-=v.z; rv[q*4+3]-=v.w;
      }
#pragma unroll
      for (int i=0;i<12;i++) ssq += rv[i]*rv[i];
    }
    float* op = out + tok*DIM + lane*12;
#pragma unroll
    for (int q=0;q<3;q++){
      float4 v;
      v.x = xq[q*4]-rv[q*4]; v.y = xq[q*4+1]-rv[q*4+1];
      v.z = xq[q*4+2]-rv[q*4+2]; v.w = xq[q*4+3]-rv[q*4+3];
      *(float4*)(op + q*4) = v;
    }
#pragma unroll
    for (int d=32; d>0; d>>=1) ssq += __shfl_down(ssq, d);
    if (lane == 0) bs[w] = ssq;
    __syncthreads();
    if (t == 0) part[blockIdx.x] = bs[0]+bs[1]+bs[2]+bs[3];
  }
}

// Fallback finalize (only when ws can't hold S and S lives in d_out).
__global__ __launch_bounds__(512) void k_fin(const float* __restrict__ x,
                                             char* __restrict__ ws,
                                             float* __restrict__ out,
                                             float* __restrict__ part){
  const int t = threadIdx.x, lane = t & 63, w = t >> 6;
  const size_t tok = (size_t)blockIdx.x * 8 + w;
  const int off[8] = {0,2,6,14,30,62,126,254};
  const int* __restrict__ idxw = (const int*)(ws + WS_IDX);
  const float* __restrict__ C32 = (const float*)(ws + WS_C32);
  int loc[8];
#pragma unroll
  for (int l=0;l<8;l++) loc[l] = idxw[tok*8 + l];
  if (lane < 8) out[(size_t)NTOK*DIM + tok*8 + lane] = (float)idxw[tok*8 + lane];

  const float4* __restrict__ xr = (const float4*)(x + tok*DIM);
  float4* __restrict__ qr = (float4*)(out + tok*DIM);
  const float4* crow[8];
#pragma unroll
  for (int l=0;l<8;l++) crow[l] = (const float4*)(C32 + (size_t)(loc[l] + off[l])*DIM);
  float ssq = 0.f;
#pragma unroll
  for (int i=0;i<3;i++){
    const int e4 = i*64 + lane;
    const float4 xv = xr[e4];
    float rx = xv.x, ry = xv.y, rz = xv.z, rw = xv.w;
    float qx = 0.f, qy = 0.f, qz = 0.f, qw = 0.f;
#pragma unroll
    for (int l=0;l<8;l++){
      const float4 cv = crow[l][e4];
      rx -= cv.x; ry -= cv.y; rz -= cv.z; rw -= cv.w;
      qx += cv.x; qy += cv.y; qz += cv.z; qw += cv.w;
      ssq += rx*rx + ry*ry + rz*rz + rw*rw;
    }
    float4 q; q.x = qx; q.y = qy; q.z = qz; q.w = qw;
    qr[e4] = q;
  }
#pragma unroll
  for (int d=32; d>0; d>>=1) ssq += __shfl_down(ssq, d);
  __shared__ float bsum[8];
  if (lane == 0) bsum[w] = ssq;
  __syncthreads();
  if (t == 0){
    float s2 = 0.f;
#pragma unroll
    for (int j=0;j<8;j++) s2 += bsum[j];
    part[blockIdx.x] = s2;
  }
}

__global__ void k_loss(const float* __restrict__ part, int n,
                       float* __restrict__ out){
  const int t = threadIdx.x;
  double s = 0.0;
  for (int i=t; i<n; i+=256) s += (double)part[i];
  __shared__ double red[256];
  red[t] = s; __syncthreads();
  for (int d=128; d>0; d>>=1){
    if (t < d) red[t] += red[t+d];
    __syncthreads();
  }
  if (t == 0)
    out[(size_t)NTOK*DIM + (size_t)NTOK*8] =
      (float)(0.25 * red[0] / (double)((size_t)NTOK * DIM));
}

extern "C" void kernel_launch(void* const* d_in, const int* in_sizes, int n_in,
                              void* d_out, int out_size, void* d_ws, size_t ws_size,
                              hipStream_t stream){
  const float* x = (const float*)d_in[0];
  char* ws = (char*)d_ws;
  float* out = (float*)d_out;
  float* part = (float*)(ws + WS_PART);
  const bool fused = ws_size >= (size_t)WS_S + (size_t)S_BYTES;
  _Float16* Sp = fused ? (_Float16*)(ws + WS_S) : (_Float16*)out;

  k_prep<<<512, 256, 0, stream>>>((const float*)d_in[1], (const float*)d_in[2],
                                  (const float*)d_in[3], (const float*)d_in[4],
                                  (const float*)d_in[5], (const float*)d_in[6],
                                  (const float*)d_in[7], (const float*)d_in[8], ws);
  k_gram<<<512, 256, 0, stream>>>(ws);
  k_gemm<<<2048, 256, 0, stream>>>(x, ws, Sp);
  if (fused){
    k_chain<1><<<16384, 256, 0, stream>>>(x, Sp, ws, out, part);
    k_loss<<<1, 256, 0, stream>>>(part, 16384, out);
  } else {
    k_chain<0><<<16384, 256, 0, stream>>>(x, Sp, ws, out, part);
    k_fin<<<8192, 512, 0, stream>>>(x, ws, out, part);
    k_loss<<<1, 256, 0, stream>>>(part, 8192, out);
  }
}

// Round 7
// 442.892 us; speedup vs baseline: 1.1841x; 1.1841x over previous
//
#include <hip/hip_runtime.h>
#include <stdint.h>

#define NTOK 65536
#define DIM  768
#define NCB  512
#define NC   510
#define TAU  0.75f

typedef _Float16 f16x8 __attribute__((ext_vector_type(8)));
typedef float f32x4 __attribute__((ext_vector_type(4)));

// ws byte offsets
#define WS_C32   0u          // 512*768*4
#define WS_CHI   1572864u    // 512*768*2   (f16)
#define WS_CNORM 3145728u    // 512*4
#define WS_G     3147776u    // 512*512*4
#define WS_IDX   4196352u    // 65536*8*4 (fallback path only)
#define WS_PART  6293504u    // 16384*4 loss partials
#define WS_S     8388608u    // S f16: 65536*512*2
#define S_BYTES  67108864u

__device__ __forceinline__ void gl_lds16(const void* g, void* l){
  __builtin_amdgcn_global_load_lds(
      (const __attribute__((address_space(1))) unsigned int*)g,
      (__attribute__((address_space(3))) unsigned int*)l,
      16, 0, 0);
}

__global__ void k_prep(const float* __restrict__ cb0, const float* __restrict__ cb1,
                       const float* __restrict__ cb2, const float* __restrict__ cb3,
                       const float* __restrict__ cb4, const float* __restrict__ cb5,
                       const float* __restrict__ cb6, const float* __restrict__ cb7,
                       char* __restrict__ ws){
  const int r = blockIdx.x, t = threadIdx.x;
  const float* srcs[8] = {cb0,cb1,cb2,cb3,cb4,cb5,cb6,cb7};
  const int off[8] = {0,2,6,14,30,62,126,254};
  const int KK[8]  = {2,4,8,16,32,64,128,256};
  const float* src = nullptr;
#pragma unroll
  for (int l=0;l<8;l++)
    if (r >= off[l] && r < off[l]+KK[l]) src = srcs[l] + (size_t)(r - off[l]) * DIM;
  float* C32 = (float*)(ws + WS_C32);
  _Float16* Chi = (_Float16*)(ws + WS_CHI);
  double ss = 0.0;
#pragma unroll
  for (int i=0;i<3;i++){
    const int e = t + i*256;
    const float v = src ? src[e] : 0.f;
    C32[(size_t)r*DIM + e] = v;
    Chi[(size_t)r*DIM + e] = (_Float16)v;
    ss += (double)v * (double)v;
  }
  __shared__ double red[256];
  red[t] = ss; __syncthreads();
  for (int sdown=128; sdown>0; sdown>>=1){
    if (t < sdown) red[t] += red[t+sdown];
    __syncthreads();
  }
  if (t == 0){
    float* cnp = (float*)(ws + WS_CNORM);
    cnp[r] = (r < NC) ? (float)red[0] : 1e30f;
  }
}

__global__ void k_gram(char* __restrict__ ws){
  const int i = blockIdx.x, t = threadIdx.x;
  const float* __restrict__ C32 = (const float*)(ws + WS_C32);
  __shared__ float row[DIM];
  for (int e=t; e<DIM; e+=256) row[e] = C32[(size_t)i*DIM + e];
  __syncthreads();
  float* __restrict__ G = (float*)(ws + WS_G);
  for (int j=t; j<NCB; j+=256){
    const float4* cj = (const float4*)(C32 + (size_t)j*DIM);
    double d = 0.0;
    for (int k=0; k<DIM/4; k++){
      const float4 b = cj[k];
      d += (double)row[4*k]*(double)b.x + (double)row[4*k+1]*(double)b.y
         + (double)row[4*k+2]*(double)b.z + (double)row[4*k+3]*(double)b.w;
    }
    G[(size_t)i*NCB + j] = (float)d;
  }
}

// S = x @ C_all^T, f16 MFMA, f32 accum, stored f16.
// 128x128 tile, BK=64, 4 waves (2Mx2N), m97-style direct staging:
//   A: f32 via global_load_lds, 16B-granule XOR swizzle (mask = ((r&7)<<1)|((r>>3)&1)),
//      converted f32->f16 at fragment read (RTE casts, same S as validated path).
//   B: f16 via global_load_lds, verified 16B-chunk XOR swizzle (r&7).
// LDS 48KB single-buffered -> 3 blocks/CU.
__global__ __launch_bounds__(256, 3) void k_gemm(const float* __restrict__ x,
                                                 const char* __restrict__ ws,
                                                 _Float16* __restrict__ S){
  __shared__ __align__(16) char smem[49152];   // A f32 [128][64] @0, B f16 [128][64] @32768
  const int t = threadIdx.x, lane = t & 63, w = t >> 6;
  const int wm = w >> 1, wn = w & 1;
  const int bid = blockIdx.x;
  const int xcd = bid & 7, jj = bid >> 3;
  const int mt = xcd*64 + (jj >> 2), nt = jj & 3;
  const _Float16* __restrict__ Chi = (const _Float16*)(ws + WS_CHI);

  f32x4 acc[4][4];
#pragma unroll
  for (int i=0;i<4;i++)
#pragma unroll
    for (int j=0;j<4;j++) acc[i][j] = {0.f,0.f,0.f,0.f};

  for (int kt=0; kt<12; kt++){
    // stage A (f32): 8 issues x 4KB. dest linear; source granule pre-swizzled.
#pragma unroll
    for (int i8=0;i8<8;i8++){
      const int r0 = w*32 + i8*4;            // wave-uniform row base (4 rows/issue)
      const int row = r0 + (lane>>4);
      const int g = lane & 15;
      const int sg = g ^ (((row&7)<<1) | ((row>>3)&1));
      const size_t go = (size_t)(mt*128 + row)*DIM + (size_t)kt*64 + sg*4;
      gl_lds16(x + go, smem + r0*256);
    }
    // stage B (f16): 4 issues x 4KB (verified pattern).
#pragma unroll
    for (int c4=0;c4<4;c4++){
      const int r0 = w*32 + c4*8;
      const int rloc = r0 + (lane>>3);
      const int jsrc = (lane&7) ^ (rloc&7);
      const size_t go = (size_t)(nt*128 + rloc)*DIM + (size_t)kt*64 + jsrc*8;
      gl_lds16(Chi + go, smem + 32768 + r0*128);
    }
    __syncthreads();
#pragma unroll
    for (int kk=0; kk<2; kk++){
      f16x8 fa[4], fb[4];
#pragma unroll
      for (int mf=0;mf<4;mf++){
        const int m = wm*64 + mf*16 + (lane&15);
        const int maskm = ((m&7)<<1) | ((m>>3)&1);
        const int ch = kk*4 + (lane>>4);
        const int g0 = (2*ch) ^ maskm;        // content granule holding src 2ch
        const f32x4 lo = *(const f32x4*)(smem + m*256 + g0*16);
        const f32x4 hi = *(const f32x4*)(smem + m*256 + (g0^1)*16);
        f16x8 r;
        r[0]=(_Float16)lo[0]; r[1]=(_Float16)lo[1]; r[2]=(_Float16)lo[2]; r[3]=(_Float16)lo[3];
        r[4]=(_Float16)hi[0]; r[5]=(_Float16)hi[1]; r[6]=(_Float16)hi[2]; r[7]=(_Float16)hi[3];
        fa[mf] = r;
      }
#pragma unroll
      for (int nf=0;nf<4;nf++){
        const int c = wn*64 + nf*16 + (lane&15);
        const uint bb = (uint)(32768 + c*128 + ((((kk<<2)+(lane>>4)) ^ (c&7))*16));
        fb[nf] = *(const f16x8*)(smem + bb);
      }
#pragma unroll
      for (int mf=0;mf<4;mf++)
#pragma unroll
        for (int nf=0;nf<4;nf++)
          acc[mf][nf] = __builtin_amdgcn_mfma_f32_16x16x32_f16(fa[mf], fb[nf], acc[mf][nf], 0,0,0);
    }
    __syncthreads();
  }

#pragma unroll
  for (int mf=0;mf<4;mf++)
#pragma unroll
    for (int nf=0;nf<4;nf++){
      const f32x4 v = acc[mf][nf];
      const int col  = nt*128 + wn*64 + nf*16 + (lane&15);
      const int row0 = mt*128 + wm*64 + mf*16 + ((lane>>4)<<2);
#pragma unroll
      for (int e=0;e<4;e++)
        S[(size_t)(row0+e)*NCB + col] = (_Float16)v[e];
    }
}

// Band-rescore argmin chain, 1 wave/token (R5 dataflow + register slimming).
// Per-lane 8-bit band mask replaces mb[8]; scores recomputed after the reduce
// (kills sc[8]). rv/ssq updates fused in-loop, overlapping the G-row latency.
// Gram correction for rescore = s0 - sv of the owner lane (f16-S error cancels).
template<int FUSED>
__global__ __launch_bounds__(256, 4) void k_chain(const float* __restrict__ x,
                                                  const _Float16* __restrict__ S,
                                                  char* __restrict__ ws,
                                                  float* __restrict__ out,
                                                  float* __restrict__ part){
  const int t = threadIdx.x, lane = t & 63, w = t >> 6;
  const size_t tok = (size_t)blockIdx.x*4 + w;
  const float* __restrict__ cn  = (const float*)(ws + WS_CNORM);
  const float* __restrict__ G   = (const float*)(ws + WS_G);
  const float* __restrict__ C32 = (const float*)(ws + WS_C32);

  float xv[12], rv[12];
  {
    const float4* xp = (const float4*)(x + tok*DIM + lane*12);
#pragma unroll
    for (int q=0;q<3;q++){
      const float4 v = xp[q];
      xv[q*4]=v.x; xv[q*4+1]=v.y; xv[q*4+2]=v.z; xv[q*4+3]=v.w;
    }
  }
#pragma unroll
  for (int i=0;i<12;i++) rv[i] = xv[i];

  float sv[8], s0[8];
  {
    const uint* sp = (const uint*)(S + tok*NCB);
#pragma unroll
    for (int j=0;j<4;j++){
      union { uint u; _Float16 h[2]; } cv;
      cv.u = sp[j*64 + lane];
      sv[2*j]   = (float)cv.h[0];
      sv[2*j+1] = (float)cv.h[1];
    }
  }
#pragma unroll
  for (int k=0;k<8;k++) s0[k] = sv[k];

  float ssq = 0.f;

  for (int l=0; l<8; ++l){
    const int cs = (2<<l) - 2;
    const int ce = cs + (2<<l);
    float bv = 3e38f; int bc = 0x7fffffff;
#pragma unroll
    for (int j=0;j<4;j++){
      const float2 c2 = *(const float2*)(cn + j*128 + lane*2);
      const int c0 = j*128 + lane*2;
      const float sA = (c0   >= cs && c0   < ce) ? (c2.x - 2.f*sv[2*j])   : 3e38f;
      const float sB = (c0+1 >= cs && c0+1 < ce) ? (c2.y - 2.f*sv[2*j+1]) : 3e38f;
      if (sA < bv){ bv = sA; bc = c0; }
      if (sB < bv){ bv = sB; bc = c0+1; }
    }
#pragma unroll
    for (int d=1; d<64; d<<=1){
      const float ov = __shfl_xor(bv, d);
      const int   oc = __shfl_xor(bc, d);
      if (ov < bv || (ov == bv && oc < bc)){ bv = ov; bc = oc; }
    }
    // recompute scores -> per-lane 8-bit band mask (saves sc[8]/mb[8] regs)
    int bm = 0;
#pragma unroll
    for (int j=0;j<4;j++){
      const float2 c2 = *(const float2*)(cn + j*128 + lane*2);
      const int c0 = j*128 + lane*2;
      const float sA = (c0   >= cs && c0   < ce) ? (c2.x - 2.f*sv[2*j])   : 3e38f;
      const float sB = (c0+1 >= cs && c0+1 < ce) ? (c2.y - 2.f*sv[2*j+1]) : 3e38f;
      if (sA <= bv + TAU) bm |= 1 << (2*j);
      if (sB <= bv + TAU) bm |= 1 << (2*j+1);
    }
    const unsigned long long lmask = __ballot(bm != 0);
    const int b0 = __ffsll((long long)lmask) - 1;
    const int bm0 = __shfl(bm, b0);
    const bool multi = (__popcll(lmask) > 1) || ((bm0 & (bm0-1)) != 0);

    int mc = bc;
    if (multi){
      double bve = 1e300; int bce = 0x7fffffff;
      unsigned long long Lm = lmask;
      while (Lm){
        const int b = __ffsll((long long)Lm) - 1; Lm &= Lm - 1;
        int mbits = __shfl(bm, b);
        while (mbits){
          const int k = __ffs(mbits) - 1; mbits &= mbits - 1;
          const int c = (k>>1)*128 + b*2 + (k&1);
          const float dkv = __shfl(s0[k] - sv[k], b);   // exact gram-corr sum
          const float* __restrict__ crow = C32 + (size_t)c*DIM + lane*12;
          double dd = 0.0;
#pragma unroll
          for (int q=0;q<3;q++){
            const float4 v = *(const float4*)(crow + q*4);
            dd += (double)xv[q*4]*v.x + (double)xv[q*4+1]*v.y
                + (double)xv[q*4+2]*v.z + (double)xv[q*4+3]*v.w;
          }
#pragma unroll
          for (int d=1; d<64; d<<=1) dd += __shfl_xor(dd, d);
          const double se = (double)cn[c] - 2.0*(dd - (double)dkv);
          if (se < bve || (se == bve && c < bce)){ bve = se; bce = c; }
        }
      }
      mc = bce;
    }

    if (lane == 0){
      if (FUSED) out[(size_t)NTOK*DIM + tok*8 + l] = (float)(mc - cs);
      else       ((int*)(ws + WS_IDX))[tok*8 + l]  = mc - cs;
    }
    if (l < 7){
      const float* __restrict__ gr = G + (size_t)mc*NCB;   // issue first: longest dep
#pragma unroll
      for (int j=0;j<4;j++){
        const float2 g2 = *(const float2*)(gr + j*128 + lane*2);
        sv[2*j] -= g2.x; sv[2*j+1] -= g2.y;
      }
    }
    if (FUSED){
      const float* __restrict__ cw = C32 + (size_t)mc*DIM + lane*12;
#pragma unroll
      for (int q=0;q<3;q++){
        const float4 v = *(const float4*)(cw + q*4);
        rv[q*4]-=v.x; rv[q*4+1]-=v.y; rv[q*4+2]-=v.z; rv[q*4+3]-=v.w;
      }
#pragma unroll
      for (int i=0;i<12;i++) ssq += rv[i]*rv[i];
    }
  }

  if (FUSED){
    float* op = out + tok*DIM + lane*12;
#pragma unroll
    for (int q=0;q<3;q++){
      float4 v;
      v.x = xv[q*4]-rv[q*4]; v.y = xv[q*4+1]-rv[q*4+1];
      v.z = xv[q*4+2]-rv[q*4+2]; v.w = xv[q*4+3]-rv[q*4+3];
      *(float4*)(op + q*4) = v;
    }
#pragma unroll
    for (int d=32; d>0; d>>=1) ssq += __shfl_down(ssq, d);
    __shared__ float bs[4];
    if (lane == 0) bs[w] = ssq;
    __syncthreads();
    if (t == 0) part[blockIdx.x] = bs[0]+bs[1]+bs[2]+bs[3];
  }
}

// Fallback finalize (only when ws can't hold S and S lives in d_out).
__global__ __launch_bounds__(512) void k_fin(const float* __restrict__ x,
                                             char* __restrict__ ws,
                                             float* __restrict__ out,
                                             float* __restrict__ part){
  const int t = threadIdx.x, lane = t & 63, w = t >> 6;
  const size_t tok = (size_t)blockIdx.x * 8 + w;
  const int off[8] = {0,2,6,14,30,62,126,254};
  const int* __restrict__ idxw = (const int*)(ws + WS_IDX);
  const float* __restrict__ C32 = (const float*)(ws + WS_C32);
  int loc[8];
#pragma unroll
  for (int l=0;l<8;l++) loc[l] = idxw[tok*8 + l];
  if (lane < 8) out[(size_t)NTOK*DIM + tok*8 + lane] = (float)idxw[tok*8 + lane];

  const float4* __restrict__ xr = (const float4*)(x + tok*DIM);
  float4* __restrict__ qr = (float4*)(out + tok*DIM);
  const float4* crow[8];
#pragma unroll
  for (int l=0;l<8;l++) crow[l] = (const float4*)(C32 + (size_t)(loc[l] + off[l])*DIM);
  float ssq = 0.f;
#pragma unroll
  for (int i=0;i<3;i++){
    const int e4 = i*64 + lane;
    const float4 xv = xr[e4];
    float rx = xv.x, ry = xv.y, rz = xv.z, rw = xv.w;
    float qx = 0.f, qy = 0.f, qz = 0.f, qw = 0.f;
#pragma unroll
    for (int l=0;l<8;l++){
      const float4 cv = crow[l][e4];
      rx -= cv.x; ry -= cv.y; rz -= cv.z; rw -= cv.w;
      qx += cv.x; qy += cv.y; qz += cv.z; qw += cv.w;
      ssq += rx*rx + ry*ry + rz*rz + rw*rw;
    }
    float4 q; q.x = qx; q.y = qy; q.z = qz; q.w = qw;
    qr[e4] = q;
  }
#pragma unroll
  for (int d=32; d>0; d>>=1) ssq += __shfl_down(ssq, d);
  __shared__ float bsum[8];
  if (lane == 0) bsum[w] = ssq;
  __syncthreads();
  if (t == 0){
    float s2 = 0.f;
#pragma unroll
    for (int j=0;j<8;j++) s2 += bsum[j];
    part[blockIdx.x] = s2;
  }
}

__global__ void k_loss(const float* __restrict__ part, int n,
                       float* __restrict__ out){
  const int t = threadIdx.x;
  double s = 0.0;
  for (int i=t; i<n; i+=256) s += (double)part[i];
  __shared__ double red[256];
  red[t] = s; __syncthreads();
  for (int d=128; d>0; d>>=1){
    if (t < d) red[t] += red[t+d];
    __syncthreads();
  }
  if (t == 0)
    out[(size_t)NTOK*DIM + (size_t)NTOK*8] =
      (float)(0.25 * red[0] / (double)((size_t)NTOK * DIM));
}

extern "C" void kernel_launch(void* const* d_in, const int* in_sizes, int n_in,
                              void* d_out, int out_size, void* d_ws, size_t ws_size,
                              hipStream_t stream){
  const float* x = (const float*)d_in[0];
  char* ws = (char*)d_ws;
  float* out = (float*)d_out;
  float* part = (float*)(ws + WS_PART);
  const bool fused = ws_size >= (size_t)WS_S + (size_t)S_BYTES;
  _Float16* Sp = fused ? (_Float16*)(ws + WS_S) : (_Float16*)out;

  k_prep<<<512, 256, 0, stream>>>((const float*)d_in[1], (const float*)d_in[2],
                                  (const float*)d_in[3], (const float*)d_in[4],
                                  (const float*)d_in[5], (const float*)d_in[6],
                                  (const float*)d_in[7], (const float*)d_in[8], ws);
  k_gram<<<512, 256, 0, stream>>>(ws);
  k_gemm<<<2048, 256, 0, stream>>>(x, ws, Sp);
  if (fused){
    k_chain<1><<<16384, 256, 0, stream>>>(x, Sp, ws, out, part);
    k_loss<<<1, 256, 0, stream>>>(part, 16384, out);
  } else {
    k_chain<0><<<16384, 256, 0, stream>>>(x, Sp, ws, out, part);
    k_fin<<<8192, 512, 0, stream>>>(x, ws, out, part);
    k_loss<<<1, 256, 0, stream>>>(part, 8192, out);
  }
}